// Round 7
// baseline (522.795 us; speedup 1.0000x reference)
//
#include <hip/hip_runtime.h>
#include <hip/hip_bf16.h>

#define C 64
#define EPS 1e-5f

// ---- bf16 pack/unpack helpers (RNE) ---------------------------------------
static __device__ __forceinline__ unsigned int f2bf(float f) {
  unsigned int x = __float_as_uint(f);
  return (x + 0x7fffu + ((x >> 16) & 1u)) >> 16;
}
static __device__ __forceinline__ float bflo2f(unsigned int p) {  // low ushort
  return __uint_as_float(p << 16);
}
static __device__ __forceinline__ float bfhi2f(unsigned int p) {  // high ushort
  return __uint_as_float(p & 0xffff0000u);
}

// ---------------------------------------------------------------------------
// Build w1 interleaved: w1i[(k/4)*4C + c*4 + (k%4)] = w1[c][k]
// (byte-identical to the round-2 PASSING version)
// ---------------------------------------------------------------------------
__global__ __launch_bounds__(256) void build_w1i_kernel(
    const float* __restrict__ w1, float* __restrict__ w1i) {
  int idx = blockIdx.x * 256 + threadIdx.x;  // 64*128 = 8192
  if (idx < C * 2 * C) {
    int c = idx / (2 * C);
    int k = idx % (2 * C);
    w1i[(k >> 2) * (4 * C) + c * 4 + (k & 3)] = w1[idx];
  }
}

// ---------------------------------------------------------------------------
// Per-node: LayerNorm -> Dense(2C) -> silu -> Dense(C) -> *vln_weight -> q
// D16[n][c] = {bf16(q*vec0), bf16(q*vec1), bf16(q*vec2), 0} packed in uint2.
// (byte-identical to the round-2 PASSING version — fp32, LDS weights)
// ---------------------------------------------------------------------------
__global__ __launch_bounds__(256, 1) void node_mlp_kernel(
    const float* __restrict__ x, const float* __restrict__ vec,
    const float* __restrict__ ln_scale, const float* __restrict__ ln_bias,
    const float* __restrict__ vln_w,
    const float* __restrict__ w1i, const float* __restrict__ b1,
    const float* __restrict__ w2, const float* __restrict__ b2,
    uint2* __restrict__ D16, int n_nodes) {
  __shared__ float w1s[2 * C * C];  // [k/4][c][4]
  __shared__ float w2s[2 * C * C];  // [k][c]
  {
    float4* d1 = (float4*)w1s;
    const float4* s1 = (const float4*)w1i;
    float4* d2 = (float4*)w2s;
    const float4* s2 = (const float4*)w2;
    for (int i = threadIdx.x; i < 2 * C * C / 4; i += 256) {
      d1[i] = s1[i];
      d2[i] = s2[i];
    }
  }
  __syncthreads();

  int n = blockIdx.x * 256 + threadIdx.x;
  if (n >= n_nodes) return;

  // ---- LayerNorm ----
  const float* xp = x + (size_t)n * C;
  float xr[C];
  float mean = 0.f;
#pragma unroll
  for (int c0 = 0; c0 < C; c0 += 4) {
    float4 v = *(const float4*)(xp + c0);
    xr[c0] = v.x; xr[c0 + 1] = v.y; xr[c0 + 2] = v.z; xr[c0 + 3] = v.w;
    mean += v.x + v.y + v.z + v.w;
  }
  mean *= (1.f / C);
  float var = 0.f;
#pragma unroll
  for (int c = 0; c < C; c++) { float d = xr[c] - mean; var += d * d; }
  var *= (1.f / C);
  float rs = rsqrtf(var + EPS);
#pragma unroll
  for (int c = 0; c < C; c++)
    xr[c] = (xr[c] - mean) * rs * ln_scale[c] + ln_bias[c];

  // ---- MLP ----
  float out[C];
#pragma unroll
  for (int c = 0; c < C; c++) out[c] = b2[c];

  for (int k0 = 0; k0 < 2 * C; k0 += 4) {
    float h0 = b1[k0], h1 = b1[k0 + 1], h2 = b1[k0 + 2], h3 = b1[k0 + 3];
    const float4* wrow = (const float4*)(w1s + k0 * C);  // [c][4]
#pragma unroll
    for (int c = 0; c < C; c++) {
      float4 w = wrow[c];  // LDS broadcast (all lanes same addr)
      float xc = xr[c];
      h0 = fmaf(xc, w.x, h0);
      h1 = fmaf(xc, w.y, h1);
      h2 = fmaf(xc, w.z, h2);
      h3 = fmaf(xc, w.w, h3);
    }
    float sv[4];
    sv[0] = h0 / (1.f + __expf(-h0));
    sv[1] = h1 / (1.f + __expf(-h1));
    sv[2] = h2 / (1.f + __expf(-h2));
    sv[3] = h3 / (1.f + __expf(-h3));
#pragma unroll
    for (int j = 0; j < 4; j++) {
      const float4* w2row = (const float4*)(w2s + (k0 + j) * C);
      float s = sv[j];
#pragma unroll
      for (int c0 = 0; c0 < C / 4; c0++) {
        float4 w = w2row[c0];  // LDS broadcast
        out[c0 * 4 + 0] = fmaf(s, w.x, out[c0 * 4 + 0]);
        out[c0 * 4 + 1] = fmaf(s, w.y, out[c0 * 4 + 1]);
        out[c0 * 4 + 2] = fmaf(s, w.z, out[c0 * 4 + 2]);
        out[c0 * 4 + 3] = fmaf(s, w.w, out[c0 * 4 + 3]);
      }
    }
  }

  // fold vln_weight into q
#pragma unroll
  for (int c = 0; c < C; c++) out[c] *= vln_w[c];

  // ---- D = q * vec, packed bf16 [n][c][{0,1,2,pad}] ----
  const float* vp = vec + (size_t)n * 3 * C;
  uint2* Dp = D16 + (size_t)n * C;
#pragma unroll
  for (int c0 = 0; c0 < C / 4; c0++) {
    float4 v0 = *(const float4*)(vp + c0 * 4);           // comp 0
    float4 v1 = *(const float4*)(vp + C + c0 * 4);       // comp 1
    float4 v2 = *(const float4*)(vp + 2 * C + c0 * 4);   // comp 2
    float q0 = out[c0 * 4 + 0], q1 = out[c0 * 4 + 1];
    float q2 = out[c0 * 4 + 2], q3 = out[c0 * 4 + 3];
    uint2 u;
    u.x = f2bf(q0 * v0.x) | (f2bf(q0 * v1.x) << 16);
    u.y = f2bf(q0 * v2.x);
    Dp[c0 * 4 + 0] = u;
    u.x = f2bf(q1 * v0.y) | (f2bf(q1 * v1.y) << 16);
    u.y = f2bf(q1 * v2.y);
    Dp[c0 * 4 + 1] = u;
    u.x = f2bf(q2 * v0.z) | (f2bf(q2 * v1.z) << 16);
    u.y = f2bf(q2 * v2.z);
    Dp[c0 * 4 + 2] = u;
    u.x = f2bf(q3 * v0.w) | (f2bf(q3 * v1.w) << 16);
    u.y = f2bf(q3 * v2.w);
    Dp[c0 * 4 + 3] = u;
  }
}

// ---------------------------------------------------------------------------
// Histogram: count[receiver]++ (int atomics -> deterministic counts)
// ---------------------------------------------------------------------------
__global__ __launch_bounds__(256) void hist_kernel(
    const int* __restrict__ receivers, int* __restrict__ count, int n_edges) {
  int e = blockIdx.x * 256 + threadIdx.x;
  if (e < n_edges) atomicAdd(&count[receivers[e]], 1);
}

// ---------------------------------------------------------------------------
// Single-block exclusive scan: row_start[0..n_nodes] from count.
// ---------------------------------------------------------------------------
__global__ __launch_bounds__(1024) void scan_kernel(
    const int* __restrict__ count, int* __restrict__ row_start, int n_nodes) {
  __shared__ int part[1024];
  int tid = threadIdx.x;
  int chunk = (n_nodes + 1023) / 1024;
  int lo = tid * chunk;
  int hi = min(lo + chunk, n_nodes);
  int s = 0;
  for (int i = lo; i < hi; i++) s += count[i];
  part[tid] = s;
  __syncthreads();
  for (int off = 1; off < 1024; off <<= 1) {
    int v = (tid >= off) ? part[tid - off] : 0;
    __syncthreads();
    part[tid] += v;
    __syncthreads();
  }
  int run = (tid == 0) ? 0 : part[tid - 1];
  for (int i = lo; i < hi; i++) { row_start[i] = run; run += count[i]; }
  if (tid == 1023) row_start[n_nodes] = part[1023];
}

// ---------------------------------------------------------------------------
// Scatter edge ids into receiver buckets (positions arbitrary; set is
// deterministic — canonical order restored by sort_kernel).
// ---------------------------------------------------------------------------
__global__ __launch_bounds__(256) void scatter_kernel(
    const int* __restrict__ receivers, const int* __restrict__ row_start,
    int* __restrict__ cursor, int* __restrict__ edge_ids, int n_edges) {
  int e = blockIdx.x * 256 + threadIdx.x;
  if (e < n_edges) {
    int r = receivers[e];
    int pos = row_start[r] + atomicAdd(&cursor[r], 1);
    edge_ids[pos] = e;
  }
}

// ---------------------------------------------------------------------------
// Per-bucket insertion sort -> canonical (ascending edge-id) order.
// ---------------------------------------------------------------------------
__global__ __launch_bounds__(256) void sort_kernel(
    int* __restrict__ edge_ids, const int* __restrict__ row_start,
    int n_nodes) {
  int n = blockIdx.x * 256 + threadIdx.x;
  if (n >= n_nodes) return;
  int lo = row_start[n], hi = row_start[n + 1];
  for (int i = lo + 1; i < hi; i++) {
    int v = edge_ids[i];
    int j = i - 1;
    while (j >= lo && edge_ids[j] > v) {
      edge_ids[j + 1] = edge_ids[j];
      j--;
    }
    edge_ids[j + 1] = v;
  }
}

// ---------------------------------------------------------------------------
// Gather-accumulate: one wave per receiver node, lane = channel.
// D_r loaded ONCE per node; bucket edges processed sequentially in sorted
// order -> bit-deterministic fp32 sum; single coalesced plain store to dx.
// No atomics touch d_out.
// ---------------------------------------------------------------------------
__global__ __launch_bounds__(256) void gather_kernel(
    const int* __restrict__ senders, const int* __restrict__ edge_ids,
    const int* __restrict__ row_start, const float* __restrict__ Mmat,
    const uint2* __restrict__ D2, float* __restrict__ dx, int n_nodes) {
  int wid = threadIdx.x >> 6;
  int lane = threadIdx.x & 63;
  int n = blockIdx.x * 4 + wid;
  if (n >= n_nodes) return;
  n = __builtin_amdgcn_readfirstlane(n);  // wave-uniform -> scalar loads

  int lo = row_start[n], hi = row_start[n + 1];
  uint2 drv = D2[(size_t)n * C + lane];
  float r0 = bflo2f(drv.x), r1 = bfhi2f(drv.x), r2 = bflo2f(drv.y);
  float acc = 0.f;
  for (int k = lo; k < hi; k++) {
    int e = edge_ids[k];   // uniform -> s_load
    int s = senders[e];    // uniform -> s_load
    uint2 dsv = D2[(size_t)s * C + lane];
    const float* M = Mmat + (size_t)e * 9;  // uniform -> s_loads
    float m00 = M[0], m01 = M[1], m02 = M[2];
    float m10 = M[3], m11 = M[4], m12 = M[5];
    float m20 = M[6], m21 = M[7], m22 = M[8];
    float s0 = bflo2f(dsv.x), s1 = bfhi2f(dsv.x), s2 = bflo2f(dsv.y);
    float f0 = m00 * s0 + m01 * s1 + m02 * s2;
    float f1 = m10 * s0 + m11 * s1 + m12 * s2;
    float f2 = m20 * s0 + m21 * s1 + m22 * s2;
    acc += r0 * f0 + r1 * f1 + r2 * f2;  // fixed sequential order
  }
  dx[(size_t)n * C + lane] = acc;
}

// ---------------------------------------------------------------------------
extern "C" void kernel_launch(void* const* d_in, const int* in_sizes, int n_in,
                              void* d_out, int out_size, void* d_ws, size_t ws_size,
                              hipStream_t stream) {
  const float* x        = (const float*)d_in[0];
  const float* vec      = (const float*)d_in[1];
  const int*   senders  = (const int*)d_in[2];
  const int*   receivers= (const int*)d_in[3];
  const float* Mmat     = (const float*)d_in[4];
  const float* ln_scale = (const float*)d_in[5];
  const float* ln_bias  = (const float*)d_in[6];
  const float* vln_w    = (const float*)d_in[7];
  const float* w1       = (const float*)d_in[8];
  const float* b1       = (const float*)d_in[9];
  const float* w2       = (const float*)d_in[10];
  const float* b2       = (const float*)d_in[11];

  int n_nodes = in_sizes[0] / C;   // 50000
  int n_edges = in_sizes[2];       // 800000

  // ws layout:
  //   D16       [N][C] uint2           25.6 MB
  //   w1i       8192 floats            32 KB
  //   count     [N] int                200 KB   } contiguous, one memset
  //   cursor    [N] int                200 KB   }
  //   row_start [N+1] int              200 KB
  //   edge_ids  [E] int                3.2 MB
  uint2* D16 = (uint2*)d_ws;
  float* w1i = (float*)(D16 + (size_t)n_nodes * C);
  int* count     = (int*)(w1i + 2 * C * C);
  int* cursor    = count + n_nodes;
  int* row_start = cursor + n_nodes;
  int* edge_ids  = row_start + n_nodes + 1;

  build_w1i_kernel<<<(C * 2 * C + 255) / 256, 256, 0, stream>>>(w1, w1i);

  node_mlp_kernel<<<(n_nodes + 255) / 256, 256, 0, stream>>>(
      x, vec, ln_scale, ln_bias, vln_w, w1i, b1, w2, b2, D16, n_nodes);

  // zero count + cursor (contiguous)
  hipMemsetAsync(count, 0, (size_t)2 * n_nodes * sizeof(int), stream);

  hist_kernel<<<(n_edges + 255) / 256, 256, 0, stream>>>(receivers, count, n_edges);
  scan_kernel<<<1, 1024, 0, stream>>>(count, row_start, n_nodes);
  scatter_kernel<<<(n_edges + 255) / 256, 256, 0, stream>>>(
      receivers, row_start, cursor, edge_ids, n_edges);
  sort_kernel<<<(n_nodes + 255) / 256, 256, 0, stream>>>(edge_ids, row_start, n_nodes);

  gather_kernel<<<(n_nodes + 3) / 4, 256, 0, stream>>>(
      senders, edge_ids, row_start, Mmat, D16, (float*)d_out, n_nodes);
}